// Round 6
// baseline (383.928 us; speedup 1.0000x reference)
//
#include <hip/hip_runtime.h>
#include <math.h>

#define IMG_H 4096
#define IMG_W 4096
#define TS 64
#define HALO 3
#define TW 70              // TS + 2*HALO
#define THS 71             // th LDS row stride (odd -> conflict-free)
#define HMS 65             // hm LDS row stride (odd)
#define NBINS 4096         // fallback: linear value bins over [-4, 4]
#define CBLK 1024          // count blocks
#define CAPB 4096          // per-block candidate region (expected ~26/block)
// speculative window: sample median of 16.7M N(0,1) is 0 +- 3.1e-4 (1 sigma);
// [-1/512, +1/512) covers +-6.3 sigma. Exact fallback path guards it.
#define WLO (-0.001953125f)
#define WHI ( 0.001953125f)
#define MCAP 1024          // member buffer for the selected sub-bin
#define NSUB 2048          // linear sub-bins across the window

struct SelState { float median; };

__device__ __forceinline__ unsigned f2u(float f) {
    unsigned b = __float_as_uint(f);
    unsigned mask = (unsigned)(-(int)(b >> 31)) | 0x80000000u;
    return b ^ mask;
}
__device__ __forceinline__ float u2f(unsigned u) {
    unsigned mask = (u >> 31) ? 0x80000000u : 0xFFFFFFFFu;
    return __uint_as_float(u ^ mask);
}
__device__ __forceinline__ int val_bin(float v) {
    float t = (v + 4.0f) * 512.0f;
    int b = (int)t;
    b = b < 0 ? 0 : b;
    b = b > (NBINS - 1) ? (NBINS - 1) : b;
    return b;
}
__device__ __forceinline__ int sub_bin(float v) {
    float t = (v - WLO) * (float)(NSUB * 256);
    int b = (int)t;
    b = b < 0 ? 0 : b;
    b = b > (NSUB - 1) ? (NSUB - 1) : b;
    return b;
}

// ---------------------------------------------------------------------------
// count + per-block compact; LAST block (device fan-in) runs median finalize.
// Fan-in: stores -> __threadfence -> __syncthreads -> t0 atomicAdd(done);
// the block observing prev==CBLK-1 proceeds (standard threadFenceReduction
// pattern; done is memset to 0 each launch since workspace is poisoned).
// Finalize fast path: unconditional statically-addressed candidate loads
// (64 regions/wave per batch, 2 batches), register-resident keys, LDS
// sub-bin histogram -> scan -> gather -> O(m^2) select. Any anomaly -> exact
// 3-pass radix fallback over full x (slow, any distribution, ~never runs).
// ---------------------------------------------------------------------------
__global__ __launch_bounds__(512, 4) void count_finalize(
    const float4* __restrict__ x4, int n4, unsigned K,
    unsigned* __restrict__ belowCnt,      // [CBLK]
    unsigned* __restrict__ candCnt,       // [CBLK]
    unsigned* __restrict__ candA,         // [CBLK * CAPB]
    unsigned* __restrict__ candB,         // fallback scratch (= d_out)
    SelState* __restrict__ st,
    unsigned* __restrict__ done)          // memset 0 per launch
{
    __shared__ unsigned buf[CAPB];        // 16 KB (count staging)
    __shared__ unsigned hist[NSUB];       // 8 KB  (finalize)
    __shared__ unsigned mem[MCAP];        // 4 KB
    __shared__ unsigned lh[NBINS];        // 16 KB (fallback)
    __shared__ unsigned ccs[CBLK];        // 4 KB
    __shared__ unsigned wsA[8], wsB[8], wsC[8], wred[8];
    __shared__ unsigned lcnt, s_lastflag;
    __shared__ unsigned s_below, s_M, s_ovf, s_sb, s_kr2, mcnt;
    __shared__ unsigned s_bin, s_krem, s_m, s_pref, s_kr;
    const int t = threadIdx.x;
    const unsigned lane = t & 63, wid = t >> 6;

    // ---------------------------- count phase ------------------------------
    if (t == 0) lcnt = 0;
    __syncthreads();
    unsigned below = 0;
    const int idx = blockIdx.x * 512 + t;
    const int stride = CBLK * 512;
    if (n4 == 8 * stride) {
        float4 v[8];
        #pragma unroll
        for (int j = 0; j < 8; j++) v[j] = x4[idx + j * stride];
        #pragma unroll
        for (int j = 0; j < 8; j++) {
            float vs[4] = {v[j].x, v[j].y, v[j].z, v[j].w};
            #pragma unroll
            for (int u = 0; u < 4; u++) {
                float vv = vs[u];
                below += (vv < WLO) ? 1u : 0u;
                if (vv >= WLO && vv < WHI) {
                    unsigned p = atomicAdd(&lcnt, 1u);
                    if (p < CAPB) buf[p] = f2u(vv);
                }
            }
        }
    } else {
        for (int i = idx; i < n4; i += stride) {
            float4 v = x4[i];
            float vs[4] = {v.x, v.y, v.z, v.w};
            #pragma unroll
            for (int u = 0; u < 4; u++) {
                float vv = vs[u];
                below += (vv < WLO) ? 1u : 0u;
                if (vv >= WLO && vv < WHI) {
                    unsigned p = atomicAdd(&lcnt, 1u);
                    if (p < CAPB) buf[p] = f2u(vv);
                }
            }
        }
    }
    #pragma unroll
    for (int off = 32; off >= 1; off >>= 1) below += __shfl_down(below, off, 64);
    if (lane == 0) wred[wid] = below;
    __syncthreads();
    if (t == 0) {
        unsigned tot = 0;
        #pragma unroll
        for (int w = 0; w < 8; w++) tot += wred[w];
        belowCnt[blockIdx.x] = tot;
        candCnt[blockIdx.x] = lcnt;
    }
    unsigned m0 = lcnt; if (m0 > CAPB) m0 = CAPB;
    const unsigned gbase = (unsigned)blockIdx.x * CAPB;
    for (unsigned i = t; i < m0; i += 512) candA[gbase + i] = buf[i];

    // ---------------------------- fan-in -----------------------------------
    __threadfence();                    // my stores device-visible
    __syncthreads();                    // all threads' stores fenced
    if (t == 0) {
        unsigned prev = atomicAdd(done, 1u);
        s_lastflag = (prev == (unsigned)(CBLK - 1)) ? 1u : 0u;
    }
    __syncthreads();
    if (!s_lastflag) return;
    __threadfence();                    // acquire side

    // ---------------------------- finalize ---------------------------------
    // stage candCnt + totals (2 entries/thread; 8 waves)
    {
        const unsigned c0 = candCnt[t], c1 = candCnt[t + 512];
        ccs[t] = c0; ccs[t + 512] = c1;
        unsigned bsum = belowCnt[t] + belowCnt[t + 512];
        unsigned csum = c0 + c1;
        unsigned osum = ((c0 > CAPB) ? 1u : 0u) + ((c1 > CAPB) ? 1u : 0u);
        #pragma unroll
        for (int off = 32; off >= 1; off >>= 1) {
            bsum += __shfl_down(bsum, off, 64);
            csum += __shfl_down(csum, off, 64);
            osum += __shfl_down(osum, off, 64);
        }
        if (lane == 0) { wsA[wid] = bsum; wsB[wid] = csum; wsC[wid] = osum; }
        if (t == 0) mcnt = 0;
        for (int i = t; i < NSUB; i += 512) hist[i] = 0;
        __syncthreads();
        if (t == 0) {
            unsigned bb = 0, cc = 0, oo = 0;
            #pragma unroll
            for (int w = 0; w < 8; w++) { bb += wsA[w]; cc += wsB[w]; oo += wsC[w]; }
            s_below = bb; s_M = cc; s_ovf = oo;
        }
        __syncthreads();
    }

    const unsigned belowT = s_below, M = s_M;
    bool resolved = false;              // uniform across block
    if (s_ovf == 0u && K >= belowT && (K - belowT) < M) {
        const unsigned kRem = K - belowT;

        // pass 1: sub-bin histogram; 2 batches x 64 unconditional loads
        #pragma unroll
        for (int half = 0; half < 2; half++) {
            const unsigned rbase = (unsigned)half * 512u + wid * 64u;
            unsigned key[64];
            #pragma unroll
            for (int g = 0; g < 64; g++)
                key[g] = candA[(rbase + (unsigned)g) * CAPB + lane];
            #pragma unroll
            for (int g = 0; g < 64; g++)
                if (lane < ccs[rbase + (unsigned)g])
                    atomicAdd(&hist[sub_bin(u2f(key[g]))], 1u);
        }
        // rare tail: regions with cc > 64
        for (int r = t; r < CBLK; r += 512) {
            const unsigned cc = ccs[r];
            for (unsigned j = 64; j < cc; j++)
                atomicAdd(&hist[sub_bin(u2f(candA[(unsigned)r * CAPB + j]))], 1u);
        }
        __syncthreads();

        // scan sub-bins (4/thread, 8 waves) -> rank-kRem sub-bin
        unsigned d[4], local = 0;
        #pragma unroll
        for (int j = 0; j < 4; j++) { d[j] = hist[t * 4 + j]; local += d[j]; }
        unsigned s = local;
        #pragma unroll
        for (int off = 1; off < 64; off <<= 1) {
            unsigned u = __shfl_up(s, off, 64);
            if (lane >= off) s += u;
        }
        if (lane == 63) wsA[wid] = s;
        __syncthreads();
        unsigned base = 0;
        for (unsigned w = 0; w < wid; w++) base += wsA[w];
        unsigned excl = base + s - local;
        if (kRem >= excl && kRem < excl + local) {
            unsigned cum = excl;
            #pragma unroll
            for (int j = 0; j < 4; j++) {
                if (kRem < cum + d[j]) { s_sb = (unsigned)(t * 4 + j); s_kr2 = kRem - cum; break; }
                cum += d[j];
            }
        }
        __syncthreads();

        // pass 2: gather selected sub-bin members (reload, L1/L2-hot)
        const unsigned sb = s_sb;
        #pragma unroll
        for (int half = 0; half < 2; half++) {
            const unsigned rbase = (unsigned)half * 512u + wid * 64u;
            unsigned key[64];
            #pragma unroll
            for (int g = 0; g < 64; g++)
                key[g] = candA[(rbase + (unsigned)g) * CAPB + lane];
            #pragma unroll
            for (int g = 0; g < 64; g++) {
                if (lane < ccs[rbase + (unsigned)g] &&
                    (unsigned)sub_bin(u2f(key[g])) == sb) {
                    unsigned p = atomicAdd(&mcnt, 1u);
                    if (p < MCAP) mem[p] = key[g];
                }
            }
        }
        for (int r = t; r < CBLK; r += 512) {
            const unsigned cc = ccs[r];
            for (unsigned j = 64; j < cc; j++) {
                unsigned k2 = candA[(unsigned)r * CAPB + j];
                if ((unsigned)sub_bin(u2f(k2)) == sb) {
                    unsigned p = atomicAdd(&mcnt, 1u);
                    if (p < MCAP) mem[p] = k2;
                }
            }
        }
        __syncthreads();
        if (mcnt <= MCAP) {
            const unsigned m = mcnt, kr2 = s_kr2;
            if ((unsigned)t < m) {
                unsigned ku = mem[t], c = 0, e = 0;
                for (unsigned j = 0; j < m; j++) {
                    unsigned kj = mem[j];
                    c += (kj < ku);
                    e += (kj == ku);
                }
                if (c <= kr2 && kr2 < c + e) st->median = u2f(ku);
            }
            resolved = true;
        }
    }
    if (resolved) return;

    // ---------------- exact fallback: 3-pass radix select ------------------
    __syncthreads();
    for (int i = t; i < NBINS; i += 512) lh[i] = 0;
    __syncthreads();
    for (int i = t; i < n4; i += 512) {
        float4 v = x4[i];
        atomicAdd(&lh[val_bin(v.x)], 1u);
        atomicAdd(&lh[val_bin(v.y)], 1u);
        atomicAdd(&lh[val_bin(v.z)], 1u);
        atomicAdd(&lh[val_bin(v.w)], 1u);
    }
    __syncthreads();
    if (t == 0) {
        unsigned cum = 0;
        for (int i = 0; i < NBINS; i++) {
            unsigned c = lh[i];
            if (K < cum + c) { s_bin = (unsigned)i; s_krem = K - cum; break; }
            cum += c;
        }
        s_m = 0;
    }
    __syncthreads();
    {
        const unsigned bin = s_bin;
        for (int i = t; i < n4; i += 512) {
            float4 v = x4[i];
            float vs[4] = {v.x, v.y, v.z, v.w};
            #pragma unroll
            for (int j = 0; j < 4; j++) {
                if ((unsigned)val_bin(vs[j]) == bin) {
                    unsigned p = atomicAdd(&s_m, 1u);
                    candB[p] = f2u(vs[j]);
                }
            }
        }
        __syncthreads();
    }
    const int M2 = (int)s_m;
    if (t == 0) { s_pref = 0; s_kr = s_krem; }
    __syncthreads();
    for (int p = 0; p < 3; p++) {
        const int shift = (p == 0) ? 21 : ((p == 1) ? 10 : 0);
        const int bits  = (p == 2) ? 10 : 11;
        const int nb    = 1 << bits;
        for (int i = t; i < nb; i += 512) lh[i] = 0;
        __syncthreads();
        const unsigned pref = s_pref;
        for (int i = t; i < M2; i += 512) {
            unsigned u = candB[i];
            bool ok = (p == 0) || ((u >> ((p == 1) ? 21 : 10)) == pref);
            if (ok) atomicAdd(&lh[(u >> shift) & (unsigned)(nb - 1)], 1u);
        }
        __syncthreads();
        if (t == 0) {
            unsigned kr = s_kr, cum = 0;
            for (int i = 0; i < nb; i++) {
                unsigned c = lh[i];
                if (kr < cum + c) { s_pref = (pref << bits) | (unsigned)i; s_kr = kr - cum; break; }
                cum += c;
            }
        }
        __syncthreads();
    }
    if (t == 0) st->median = u2f(s_pref);
}

// -------- fused threshold + 7x7 maxpool (pad=-inf) + binarize + multiply ----
// Unchanged from the round-4 verified kernel. 512 threads, 37 KB LDS ->
// 4 blocks/CU; interior blocks (94%) take a check-free staging path.
__global__ __launch_bounds__(512) void nms_kernel(
    const float* __restrict__ x, float* __restrict__ out,
    const SelState* __restrict__ st)
{
    __shared__ float th[TW * THS];   // 19.4 KB
    __shared__ float hm[TW * HMS];   // 17.8 KB

    const float med = st->median;
    const float NEGINF = -__builtin_inff();
    const int bx = blockIdx.x, by = blockIdx.y;
    const int gy0 = by * TS - HALO;
    const int gcol0 = bx * TS - 4;       // float4-aligned staging start

    if (bx >= 1 && bx <= 62 && by >= 1 && by <= 62) {
        #pragma unroll
        for (int k = 0; k < 3; k++) {
            int task = threadIdx.x + k * 512;
            if (task < TW * 18) {
                int r = task / 18, q = task - r * 18;
                const float4 v = *(const float4*)&x[(gy0 + r) * IMG_W + (gcol0 + q * 4)];
                float vs[4] = {v.x, v.y, v.z, v.w};
                #pragma unroll
                for (int cmp = 0; cmp < 4; cmp++) {
                    int c = q * 4 - 1 + cmp;
                    if ((unsigned)c < (unsigned)TW)
                        th[r * THS + c] = (vs[cmp] < med) ? 0.0f : vs[cmp];
                }
            }
        }
    } else {
        for (int task = threadIdx.x; task < TW * 18; task += 512) {
            int r = task / 18, q = task - r * 18;
            int gy = gy0 + r;
            int gxb = gcol0 + q * 4;
            bool rowok = (gy >= 0 && gy < IMG_H);
            float vs[4];
            if (rowok && gxb >= 0 && gxb + 4 <= IMG_W) {
                float4 v = *(const float4*)&x[gy * IMG_W + gxb];
                vs[0] = v.x; vs[1] = v.y; vs[2] = v.z; vs[3] = v.w;
            } else if (rowok) {
                #pragma unroll
                for (int cmp = 0; cmp < 4; cmp++) {
                    int gx = gxb + cmp;
                    vs[cmp] = (gx >= 0 && gx < IMG_W) ? x[gy * IMG_W + gx] : NEGINF;
                }
            } else {
                vs[0] = vs[1] = vs[2] = vs[3] = NEGINF;
            }
            #pragma unroll
            for (int cmp = 0; cmp < 4; cmp++) {
                int c = q * 4 - 1 + cmp;
                if ((unsigned)c < (unsigned)TW) {
                    float v = vs[cmp];
                    v = (v == NEGINF) ? v : ((v < med) ? 0.0f : v);
                    th[r * THS + c] = v;
                }
            }
        }
    }
    __syncthreads();

    // horizontal 7-max: 560 tasks = 70 rows x 8 chunks of 8 outputs
    for (int task = threadIdx.x; task < TW * 8; task += 512) {
        int r = task % TW;
        int c0 = (task / TW) * 8;
        float w[7];
        #pragma unroll
        for (int i = 0; i < 14; i++) {
            w[i % 7] = th[r * THS + c0 + i];
            if (i >= 6) {
                float m = w[0];
                #pragma unroll
                for (int k = 1; k < 7; k++) m = fmaxf(m, w[k]);
                hm[r * HMS + c0 + i - 6] = m;
            }
        }
    }
    __syncthreads();

    // vertical 7-max + binarize*x: 64 cols x 8 chunks of 8 rows
    {
        const int c = threadIdx.x & 63;
        const int rr0 = (threadIdx.x >> 6) * 8;
        float w[7];
        #pragma unroll
        for (int i = 0; i < 14; i++) {
            w[i % 7] = hm[(rr0 + i) * HMS + c];
            if (i >= 6) {
                int R = rr0 + i - 6;
                float m = w[0];
                #pragma unroll
                for (int k = 1; k < 7; k++) m = fmaxf(m, w[k]);
                float tv = th[(R + HALO) * THS + (c + HALO)];
                int gy = by * TS + R;
                int gx = bx * TS + c;
                float o = 0.0f;
                if (tv == m) {
                    o = (tv != 0.0f) ? tv : x[gy * IMG_W + gx];
                }
                out[gy * IMG_W + gx] = o;
            }
        }
    }
}

extern "C" void kernel_launch(void* const* d_in, const int* in_sizes, int n_in,
                              void* d_out, int out_size, void* d_ws, size_t ws_size,
                              hipStream_t stream)
{
    const float* x = (const float*)d_in[0];
    float* out = (float*)d_out;
    const int n = in_sizes[0];                  // 16777216
    const unsigned K = (unsigned)((n - 1) / 2); // rank of lower-middle element

    char* ws = (char*)d_ws;
    SelState* st       = (SelState*)ws;                  // written every launch
    unsigned* done     = (unsigned*)(ws + 64);           // memset 0 below
    unsigned* belowCnt = (unsigned*)(ws + 16384);        // [CBLK]
    unsigned* candCnt  = (unsigned*)(ws + 24576);        // [CBLK]
    unsigned* candA    = (unsigned*)(ws + ws_size / 2);  // per-block regions

    const int n4 = n / 4;
    hipMemsetAsync(done, 0, 4, stream);          // fan-in counter (ws poisoned)
    count_finalize<<<CBLK, 512, 0, stream>>>((const float4*)x, n4, K,
                                             belowCnt, candCnt, candA,
                                             (unsigned*)d_out, st, done);
    dim3 fg(IMG_W / TS, IMG_H / TS);
    nms_kernel<<<fg, 512, 0, stream>>>(x, out, st);
}

// Round 7
// 145.964 us; speedup vs baseline: 2.6303x; 2.6303x over previous
//
#include <hip/hip_runtime.h>
#include <math.h>

#define IMG_H 4096
#define IMG_W 4096
#define TS 64
#define HALO 3
#define TW 70              // TS + 2*HALO
#define THS 71             // th LDS row stride (odd -> conflict-free)
#define HMS 65             // hm LDS row stride (odd)
#define NBINS 4096         // fallback: linear value bins over [-4, 4]
#define CBLK 1024          // count_compact grid blocks
#define CAPB 4096          // per-block candidate region (expected ~26/block)
// speculative window: sample median of 16.7M N(0,1) is 0 +- 3.1e-4 (1 sigma);
// [-1/512, +1/512) covers +-6.3 sigma. Exact fallback path guards it.
#define WLO (-0.001953125f)
#define WHI ( 0.001953125f)
#define MCAP 1024          // member buffer for the selected sub-bin
#define NSUB 2048          // linear sub-bins across the window

struct SelState { float median; };

__device__ __forceinline__ unsigned f2u(float f) {
    unsigned b = __float_as_uint(f);
    unsigned mask = (unsigned)(-(int)(b >> 31)) | 0x80000000u;
    return b ^ mask;
}
__device__ __forceinline__ float u2f(unsigned u) {
    unsigned mask = (u >> 31) ? 0x80000000u : 0xFFFFFFFFu;
    return __uint_as_float(u ^ mask);
}

// fallback-only: monotone value->bin map
__device__ __forceinline__ int val_bin(float v) {
    float t = (v + 4.0f) * 512.0f;
    int b = (int)t;
    b = b < 0 ? 0 : b;
    b = b > (NBINS - 1) ? (NBINS - 1) : b;
    return b;
}

// sub-bin map over the window [WLO, WHI)
__device__ __forceinline__ int sub_bin(float v) {
    float t = (v - WLO) * (float)(NSUB * 256);
    int b = (int)t;
    b = b < 0 ? 0 : b;
    b = b > (NSUB - 1) ? (NSUB - 1) : b;
    return b;
}

// ONE full read, ZERO global atomics: register count of (x < WLO) + LDS-staged
// compaction of window candidates into a PER-BLOCK global region. Per-block
// counts are written unconditionally -> no workspace memset needed.
// NOTE (r6 lesson): do NOT fold finalize in here via threadfence fan-in —
// device-scope fences flush non-coherent XCD L2s and cost 10-20x the
// dispatch boundary they replace.
__global__ __launch_bounds__(512, 8) void count_compact(
    const float4* __restrict__ x4, int n4,
    unsigned* __restrict__ belowCnt,      // [CBLK], plain stores
    unsigned* __restrict__ candCnt,       // [CBLK], raw count (may exceed CAPB)
    unsigned* __restrict__ candA)         // [CBLK * CAPB]
{
    __shared__ unsigned buf[CAPB];        // 16 KB staging
    __shared__ unsigned wred[8];
    __shared__ unsigned lcnt;
    const int t = threadIdx.x;
    if (t == 0) lcnt = 0;
    __syncthreads();

    unsigned below = 0;
    const int idx = blockIdx.x * 512 + t;
    const int stride = CBLK * 512;

    if (n4 == 8 * stride) {
        // exact-fit fast path: batch all 8 loads first -> 8-deep MLP,
        // independent of the rare candidate branch below.
        float4 v[8];
        #pragma unroll
        for (int j = 0; j < 8; j++) v[j] = x4[idx + j * stride];
        #pragma unroll
        for (int j = 0; j < 8; j++) {
            float vs[4] = {v[j].x, v[j].y, v[j].z, v[j].w};
            #pragma unroll
            for (int u = 0; u < 4; u++) {
                float vv = vs[u];
                below += (vv < WLO) ? 1u : 0u;
                if (vv >= WLO && vv < WHI) {
                    unsigned p = atomicAdd(&lcnt, 1u);
                    if (p < CAPB) buf[p] = f2u(vv);
                }
            }
        }
    } else {
        for (int i = idx; i < n4; i += stride) {
            float4 v = x4[i];
            float vs[4] = {v.x, v.y, v.z, v.w};
            #pragma unroll
            for (int u = 0; u < 4; u++) {
                float vv = vs[u];
                below += (vv < WLO) ? 1u : 0u;
                if (vv >= WLO && vv < WHI) {
                    unsigned p = atomicAdd(&lcnt, 1u);
                    if (p < CAPB) buf[p] = f2u(vv);
                }
            }
        }
    }

    #pragma unroll
    for (int off = 32; off >= 1; off >>= 1) below += __shfl_down(below, off, 64);
    if ((t & 63) == 0) wred[t >> 6] = below;
    __syncthreads();                       // wred + lcnt final
    if (t == 0) {
        unsigned tot = 0;
        #pragma unroll
        for (int w = 0; w < 8; w++) tot += wred[w];
        belowCnt[blockIdx.x] = tot;
        candCnt[blockIdx.x] = lcnt;        // raw; > CAPB signals overflow
    }
    unsigned m = lcnt; if (m > CAPB) m = CAPB;
    const unsigned gbase = (unsigned)blockIdx.x * CAPB;
    for (unsigned i = t; i < m; i += 512) candA[gbase + i] = buf[i];
}

// Single block, 1024 threads. Fast path: candidate keys are loaded ONCE into
// registers with UNCONDITIONAL, statically-addressed loads (64/thread, fully
// unrolled -> one latency round, issued before the count reduction even
// resolves). Both the histogram pass and the member-gather pass run from
// registers; predicates come from an LDS-staged copy of candCnt.
// Fallback: exact 3-pass radix select over full x (slow ~1 ms, any input).
__global__ __launch_bounds__(1024) void finalize_fb(
    const float4* __restrict__ x4, int n4, unsigned K,
    const unsigned* __restrict__ belowCnt,
    const unsigned* __restrict__ candCnt,
    const unsigned* __restrict__ candA,
    unsigned* __restrict__ candB,          // fallback scratch (= d_out)
    SelState* __restrict__ st)
{
    __shared__ unsigned hist[NSUB];        // 8 KB  (direct path)
    __shared__ unsigned mem[MCAP];         // 4 KB
    __shared__ unsigned lh[NBINS];         // 16 KB (fallback path)
    __shared__ unsigned ccs[CBLK];         // 4 KB  (staged candCnt)
    __shared__ unsigned wsA[16], wsB[16], wsC[16];
    __shared__ unsigned s_below, s_M, s_ovf, s_sb, s_kr2, mcnt;
    __shared__ unsigned s_bin, s_krem, s_m, s_pref, s_kr;
    const int t = threadIdx.x;
    const unsigned lane = t & 63, wid = t >> 6;

    // Issue ALL candidate loads up front: wave w owns regions [w*64, w*64+64),
    // lane l reads word l of each region. Addresses are static -> 64
    // independent loads, fully pipelined, overlapping everything below.
    const unsigned rbase = wid * 64u;
    unsigned key[64];
    #pragma unroll
    for (int g = 0; g < 64; g++)
        key[g] = candA[(rbase + (unsigned)g) * CAPB + lane];

    // sums over CBLK == blockDim == 1024 (+ stage candCnt into LDS)
    {
        const unsigned cc = candCnt[t];
        ccs[t] = cc;
        unsigned bsum = belowCnt[t];
        unsigned csum = cc;
        unsigned osum = (cc > CAPB) ? 1u : 0u;
        #pragma unroll
        for (int off = 32; off >= 1; off >>= 1) {
            bsum += __shfl_down(bsum, off, 64);
            csum += __shfl_down(csum, off, 64);
            osum += __shfl_down(osum, off, 64);
        }
        if (lane == 0) { wsA[wid] = bsum; wsB[wid] = csum; wsC[wid] = osum; }
        if (t == 0) mcnt = 0;
        for (int i = t; i < NSUB; i += 1024) hist[i] = 0;
        __syncthreads();
        if (t == 0) {
            unsigned b = 0, c = 0, o = 0;
            #pragma unroll
            for (int w = 0; w < 16; w++) { b += wsA[w]; c += wsB[w]; o += wsC[w]; }
            s_below = b; s_M = c; s_ovf = o;
        }
        __syncthreads();
    }

    const unsigned below = s_below, M = s_M;
    bool resolved = false;                 // uniform across the block
    if (s_ovf == 0u && K >= below && (K - below) < M) {
        const unsigned kRem = K - below;

        // pass 1: sub-bin histogram from registers (predicate = LDS read)
        #pragma unroll
        for (int g = 0; g < 64; g++)
            if (lane < ccs[rbase + (unsigned)g])
                atomicAdd(&hist[sub_bin(u2f(key[g]))], 1u);
        // rare tail: regions with cc > 64 (Poisson(~26): never in practice)
        for (int r = t; r < CBLK; r += 1024) {
            const unsigned cc = ccs[r];
            for (unsigned j = 64; j < cc; j++)
                atomicAdd(&hist[sub_bin(u2f(candA[(unsigned)r * CAPB + j]))], 1u);
        }
        __syncthreads();

        // scan sub-bins (2/thread) -> rank-kRem sub-bin
        unsigned d0 = hist[t * 2], d1 = hist[t * 2 + 1];
        unsigned loc2 = d0 + d1;
        unsigned s2 = loc2;
        #pragma unroll
        for (int off = 1; off < 64; off <<= 1) {
            unsigned u = __shfl_up(s2, off, 64);
            if (lane >= off) s2 += u;
        }
        if (lane == 63) wsA[wid] = s2;
        __syncthreads();
        unsigned base2 = 0;
        for (unsigned w = 0; w < wid; w++) base2 += wsA[w];
        unsigned excl2 = base2 + s2 - loc2;
        if (kRem >= excl2 && kRem < excl2 + loc2) {
            if (kRem < excl2 + d0) { s_sb = (unsigned)(t * 2);     s_kr2 = kRem - excl2; }
            else                   { s_sb = (unsigned)(t * 2 + 1); s_kr2 = kRem - excl2 - d0; }
        }
        __syncthreads();

        // pass 2: gather members of the selected sub-bin FROM REGISTERS
        const int sb = (int)s_sb;
        #pragma unroll
        for (int g = 0; g < 64; g++) {
            if (lane < ccs[rbase + (unsigned)g] &&
                sub_bin(u2f(key[g])) == sb) {
                unsigned p = atomicAdd(&mcnt, 1u);
                if (p < MCAP) mem[p] = key[g];
            }
        }
        for (int r = t; r < CBLK; r += 1024) {
            const unsigned cc = ccs[r];
            for (unsigned j = 64; j < cc; j++) {
                unsigned k2 = candA[(unsigned)r * CAPB + j];
                if (sub_bin(u2f(k2)) == sb) {
                    unsigned p = atomicAdd(&mcnt, 1u);
                    if (p < MCAP) mem[p] = k2;
                }
            }
        }
        __syncthreads();
        if (mcnt <= MCAP) {
            // O(m^2) rank-count select among m members (m ~ 13)
            const unsigned m = mcnt, kr2 = s_kr2;
            if ((unsigned)t < m) {
                unsigned ku = mem[t], c = 0, e = 0;
                for (unsigned j = 0; j < m; j++) {
                    unsigned kj = mem[j];
                    c += (kj < ku);
                    e += (kj == ku);
                }
                if (c <= kr2 && kr2 < c + e) st->median = u2f(ku);
            }
            resolved = true;
        }
    }
    if (resolved) return;

    // ---------------- exact fallback: 3-pass radix select ----------------
    __syncthreads();
    for (int i = t; i < NBINS; i += 1024) lh[i] = 0;
    __syncthreads();
    for (int i = t; i < n4; i += 1024) {
        float4 v = x4[i];
        atomicAdd(&lh[val_bin(v.x)], 1u);
        atomicAdd(&lh[val_bin(v.y)], 1u);
        atomicAdd(&lh[val_bin(v.z)], 1u);
        atomicAdd(&lh[val_bin(v.w)], 1u);
    }
    __syncthreads();

    {   // scan 4 bins/thread -> rank-K bin
        unsigned cb[4];
        unsigned local = 0;
        #pragma unroll
        for (int j = 0; j < 4; j++) { cb[j] = lh[t * 4 + j]; local += cb[j]; }
        unsigned s = local;
        #pragma unroll
        for (int off = 1; off < 64; off <<= 1) {
            unsigned u = __shfl_up(s, off, 64);
            if (lane >= off) s += u;
        }
        if (lane == 63) wsA[wid] = s;
        __syncthreads();
        unsigned base = 0;
        for (unsigned w = 0; w < wid; w++) base += wsA[w];
        unsigned excl = base + s - local;
        if (K >= excl && K < excl + local) {
            unsigned cum = excl;
            #pragma unroll
            for (int j = 0; j < 4; j++) {
                if (K < cum + cb[j]) { s_bin = (unsigned)(t * 4 + j); s_krem = K - cum; break; }
                cum += cb[j];
            }
        }
        if (t == 0) s_m = 0;
        __syncthreads();
    }

    {   // compact the selected bin's keys to candB (global scatter)
        const int b = (int)s_bin;
        for (int i = t; i < n4; i += 1024) {
            float4 v = x4[i];
            float vs[4] = {v.x, v.y, v.z, v.w};
            #pragma unroll
            for (int j = 0; j < 4; j++) {
                if (val_bin(vs[j]) == b) {
                    unsigned p = atomicAdd(&s_m, 1u);
                    candB[p] = f2u(vs[j]);
                }
            }
        }
        __syncthreads();
    }

    const int M2 = (int)s_m;
    if (t == 0) { s_pref = 0; s_kr = s_krem; }
    for (int p = 0; p < 3; p++) {
        const int shift = (p == 0) ? 21 : ((p == 1) ? 10 : 0);
        const int bits  = (p == 2) ? 10 : 11;
        const int nb    = 1 << bits;
        for (int i = t; i < nb; i += 1024) lh[i] = 0;
        __syncthreads();
        const unsigned pref = s_pref;
        for (int i = t; i < M2; i += 1024) {
            unsigned u = candB[i];
            bool ok = (p == 0) || ((u >> ((p == 1) ? 21 : 10)) == pref);
            if (ok) atomicAdd(&lh[(u >> shift) & (unsigned)(nb - 1)], 1u);
        }
        __syncthreads();
        const int P = nb >> 10;           // 2 or 1 bins/thread
        unsigned c0 = lh[t * (P ? P : 1)];
        unsigned c1 = (P == 2) ? lh[t * 2 + 1] : 0u;
        if (P == 0) { c0 = (t < nb) ? lh[t] : 0u; c1 = 0u; }
        unsigned local = c0 + c1;
        unsigned s = local;
        #pragma unroll
        for (int off = 1; off < 64; off <<= 1) {
            unsigned u = __shfl_up(s, off, 64);
            if (lane >= off) s += u;
        }
        if (lane == 63) wsA[wid] = s;
        __syncthreads();
        unsigned base = 0;
        for (unsigned w = 0; w < wid; w++) base += wsA[w];
        unsigned excl = base + s - local;
        unsigned kRem2 = s_kr;
        __syncthreads();
        if (kRem2 >= excl && kRem2 < excl + local) {
            if (P == 2) {
                if (kRem2 < excl + c0) { s_pref = (pref << bits) | (unsigned)(t * 2);     s_kr = kRem2 - excl; }
                else                   { s_pref = (pref << bits) | (unsigned)(t * 2 + 1); s_kr = kRem2 - excl - c0; }
            } else {
                s_pref = (pref << bits) | (unsigned)t;
                s_kr = kRem2 - excl;
            }
        }
        __syncthreads();
    }
    if (t == 0) st->median = u2f(s_pref);
}

// -------- fused threshold + 7x7 maxpool (pad=-inf) + binarize + multiply ----
// 512 threads, 37 KB LDS -> 4 blocks/CU. Interior blocks (94%) take a
// check-free staging path.
__global__ __launch_bounds__(512) void nms_kernel(
    const float* __restrict__ x, float* __restrict__ out,
    const SelState* __restrict__ st)
{
    __shared__ float th[TW * THS];   // 19.4 KB
    __shared__ float hm[TW * HMS];   // 17.8 KB

    const float med = st->median;
    const float NEGINF = -__builtin_inff();
    const int bx = blockIdx.x, by = blockIdx.y;
    const int gy0 = by * TS - HALO;
    const int gcol0 = bx * TS - 4;       // float4-aligned staging start

    if (bx >= 1 && bx <= (IMG_W / TS) - 2 && by >= 1 && by <= (IMG_H / TS) - 2) {
        // interior: every load in-bounds, no NEGINF handling
        #pragma unroll
        for (int k = 0; k < 3; k++) {
            int task = threadIdx.x + k * 512;
            if (task < TW * 18) {
                int r = task / 18, q = task - r * 18;
                const float4 v = *(const float4*)&x[(gy0 + r) * IMG_W + (gcol0 + q * 4)];
                float vs[4] = {v.x, v.y, v.z, v.w};
                #pragma unroll
                for (int cmp = 0; cmp < 4; cmp++) {
                    int c = q * 4 - 1 + cmp;
                    if ((unsigned)c < (unsigned)TW)
                        th[r * THS + c] = (vs[cmp] < med) ? 0.0f : vs[cmp];
                }
            }
        }
    } else {
        for (int task = threadIdx.x; task < TW * 18; task += 512) {
            int r = task / 18, q = task - r * 18;
            int gy = gy0 + r;
            int gxb = gcol0 + q * 4;
            bool rowok = (gy >= 0 && gy < IMG_H);
            float vs[4];
            if (rowok && gxb >= 0 && gxb + 4 <= IMG_W) {
                float4 v = *(const float4*)&x[gy * IMG_W + gxb];
                vs[0] = v.x; vs[1] = v.y; vs[2] = v.z; vs[3] = v.w;
            } else if (rowok) {
                #pragma unroll
                for (int cmp = 0; cmp < 4; cmp++) {
                    int gx = gxb + cmp;
                    vs[cmp] = (gx >= 0 && gx < IMG_W) ? x[gy * IMG_W + gx] : NEGINF;
                }
            } else {
                vs[0] = vs[1] = vs[2] = vs[3] = NEGINF;
            }
            #pragma unroll
            for (int cmp = 0; cmp < 4; cmp++) {
                int c = q * 4 - 1 + cmp;
                if ((unsigned)c < (unsigned)TW) {
                    float v = vs[cmp];
                    v = (v == NEGINF) ? v : ((v < med) ? 0.0f : v);
                    th[r * THS + c] = v;
                }
            }
        }
    }
    __syncthreads();

    // horizontal 7-max: 560 tasks = 70 rows x 8 chunks of 8 outputs
    for (int task = threadIdx.x; task < TW * 8; task += 512) {
        int r = task % TW;
        int c0 = (task / TW) * 8;
        float w[7];
        #pragma unroll
        for (int i = 0; i < 14; i++) {
            w[i % 7] = th[r * THS + c0 + i];
            if (i >= 6) {
                float m = w[0];
                #pragma unroll
                for (int k = 1; k < 7; k++) m = fmaxf(m, w[k]);
                hm[r * HMS + c0 + i - 6] = m;
            }
        }
    }
    __syncthreads();

    // vertical 7-max + binarize*x: 64 cols x 8 chunks of 8 rows
    {
        const int c = threadIdx.x & 63;
        const int rr0 = (threadIdx.x >> 6) * 8;
        float w[7];
        #pragma unroll
        for (int i = 0; i < 14; i++) {
            w[i % 7] = hm[(rr0 + i) * HMS + c];
            if (i >= 6) {
                int R = rr0 + i - 6;
                float m = w[0];
                #pragma unroll
                for (int k = 1; k < 7; k++) m = fmaxf(m, w[k]);
                float t = th[(R + HALO) * THS + (c + HALO)];
                int gy = by * TS + R;
                int gx = bx * TS + c;
                float o = 0.0f;
                if (t == m) {
                    o = (t != 0.0f) ? t : x[gy * IMG_W + gx];
                }
                out[gy * IMG_W + gx] = o;
            }
        }
    }
}

extern "C" void kernel_launch(void* const* d_in, const int* in_sizes, int n_in,
                              void* d_out, int out_size, void* d_ws, size_t ws_size,
                              hipStream_t stream)
{
    const float* x = (const float*)d_in[0];
    float* out = (float*)d_out;
    const int n = in_sizes[0];                  // 16777216
    const unsigned K = (unsigned)((n - 1) / 2); // rank of lower-middle element

    char* ws = (char*)d_ws;
    SelState* st       = (SelState*)ws;                  // written every launch
    unsigned* belowCnt = (unsigned*)(ws + 1024);         // [CBLK], fully rewritten
    unsigned* candCnt  = (unsigned*)(ws + 1024 + 4096);  // [CBLK], fully rewritten
    unsigned* candA    = (unsigned*)(ws + ws_size / 2);  // per-block regions

    const int n4 = n / 4;
    // 3 dispatches, no memset: all state written unconditionally each launch.
    count_compact<<<CBLK, 512, 0, stream>>>((const float4*)x, n4,
                                            belowCnt, candCnt, candA);
    finalize_fb<<<1, 1024, 0, stream>>>((const float4*)x, n4, K,
                                        belowCnt, candCnt, candA,
                                        (unsigned*)d_out, st);
    dim3 fg(IMG_W / TS, IMG_H / TS);
    nms_kernel<<<fg, 512, 0, stream>>>(x, out, st);
}